// Round 7
// baseline (218.603 us; speedup 1.0000x reference)
//
#include <hip/hip_runtime.h>

typedef __attribute__((ext_vector_type(8))) short short8;
typedef __attribute__((ext_vector_type(4))) float f32x4;
typedef __attribute__((ext_vector_type(4))) unsigned int u32x4;
typedef __attribute__((ext_vector_type(4))) unsigned short u16x4;

constexpr int cB = 2, cN = 4096, cE = 256, cH = 8, cHS = 32;

__device__ __forceinline__ unsigned short f2bf(float f) {
    unsigned int u = __builtin_bit_cast(unsigned int, f);
    u = (u + 0x7FFFu + ((u >> 16) & 1u)) >> 16;
    return (unsigned short)u;
}

__device__ __forceinline__ unsigned int cvt_pk_bf16(float lo, float hi) {
    unsigned int r;
    asm("v_cvt_pk_bf16_f32 %0, %1, %2" : "=v"(r) : "v"(lo), "v"(hi));
    return r;
}

// ---- f32 -> bf16 convert: node features (2M elems, 4/thread) ----
__global__ __launch_bounds__(256) void cvt_x_kernel(const float* __restrict__ x,
                                                    unsigned short* __restrict__ xb) {
    int t = blockIdx.x * 256 + threadIdx.x;   // 524288 threads exactly
    f32x4 v = *((const f32x4*)x + t);
    u16x4 o = { f2bf(v[0]), f2bf(v[1]), f2bf(v[2]), f2bf(v[3]) };
    *((u16x4*)xb + t) = o;
}

// ---- f32 -> bf16 convert: Wq|Wk|Wv -> Wcb[768][256] ----
__global__ __launch_bounds__(256) void cvt_w_kernel(const float* __restrict__ Wq,
                                                    const float* __restrict__ Wk,
                                                    const float* __restrict__ Wv,
                                                    unsigned short* __restrict__ wcb) {
    int t = blockIdx.x * 256 + threadIdx.x;   // 49152 threads exactly
    int f = t * 4;
    int o = f >> 8, i = f & 255;
    const float* src = (o < 256) ? Wq : (o < 512 ? Wk : Wv);
    f32x4 v = *(const f32x4*)(src + (size_t)(o & 255) * 256 + i);
    u16x4 ov = { f2bf(v[0]), f2bf(v[1]), f2bf(v[2]), f2bf(v[3]) };
    *((u16x4*)wcb + t) = ov;
}

// ---- adjacency (4-byte elems, nonzero == edge) -> bitmask, 64 bits/wave ----
__global__ __launch_bounds__(256) void bitpack_kernel(const int* __restrict__ adj,
                                                      unsigned long long* __restrict__ mask) {
    int lane = threadIdx.x & 63;
    int wave = blockIdx.x * 4 + (threadIdx.x >> 6);
    const int nwaves = 2048 * 4;
    const int nwords = cB * cN * cN / 64;     // 524288
    for (int w = wave; w < nwords; w += nwaves) {
        int v = adj[(size_t)w * 64 + lane];
        unsigned long long bal = __ballot(v != 0);
        if (lane == 0) mask[w] = bal;
    }
}

// ---- QKV projection: C[8192][768] = Xb @ Wcb^T + bias, MFMA 16x16x32 bf16 ----
// Q stored [b][h][n][32] bf16, PRE-SCALED by log2(e)/sqrt(HS) so attention can
// use exp2 on the raw QK^T output. K stored [b][h][n][32].
// V stored transposed AND k'-permuted within each 32-block of n:
//   Vt[h][hs][ (n&~31) + 2*(n&15) + ((n>>4)&1) ] = V[n][hs]
// matching the in-register P fragment order of the swapped-QK^T attention
// (lane elem e of group g holds key 4g+(e>>1)+16*(e&1)).
__global__ __launch_bounds__(256) void qkv_proj_kernel(const unsigned short* __restrict__ xb,
                                                       const unsigned short* __restrict__ wcb,
                                                       const float* __restrict__ bq,
                                                       const float* __restrict__ bk,
                                                       const float* __restrict__ bv,
                                                       unsigned short* __restrict__ Qb,
                                                       unsigned short* __restrict__ Kb,
                                                       unsigned short* __restrict__ Vt) {
    const int wv = threadIdx.x >> 6, lane = threadIdx.x & 63;
    const int col = lane & 15, grp = lane >> 4;
    const int rowbase = blockIdx.x * 64 + wv * 16;   // 16 rows per wave
    const int colbase = blockIdx.y * 64;             // 64 cols per block
    const float CE = 1.4426950408889634f * 0.17677669529663687f;  // log2(e)/sqrt(32)
    f32x4 acc[4] = {};
    for (int kk = 0; kk < 8; ++kk) {
        short8 a = *(const short8*)(xb + (size_t)(rowbase + col) * 256 + kk * 32 + grp * 8);
        #pragma unroll
        for (int c = 0; c < 4; ++c) {
            short8 bf = *(const short8*)(wcb + (size_t)(colbase + c * 16 + col) * 256 + kk * 32 + grp * 8);
            acc[c] = __builtin_amdgcn_mfma_f32_16x16x32_bf16(a, bf, acc[c], 0, 0, 0);
        }
    }
    #pragma unroll
    for (int c = 0; c < 4; ++c) {
        const int o = colbase + c * 16 + col;        // lane's output column
        const int sel = o >> 8, oo = o & 255;
        const float bias = (sel == 0 ? bq : sel == 1 ? bk : bv)[oo];
        const int h = oo >> 5, hs = oo & 31;
        const int R0 = rowbase + grp * 4;            // 4 consecutive rows per lane
        const int b = R0 >> 12, n0 = R0 & 4095;
        if (sel == 0) {
            #pragma unroll
            for (int r = 0; r < 4; ++r)
                Qb[(size_t)((b * cH + h) * cN + n0 + r) * cHS + hs] = f2bf((acc[c][r] + bias) * CE);
        } else if (sel == 1) {
            #pragma unroll
            for (int r = 0; r < 4; ++r)
                Kb[(size_t)((b * cH + h) * cN + n0 + r) * cHS + hs] = f2bf(acc[c][r] + bias);
        } else {
            unsigned short* vrow = Vt + (size_t)((b * cH + h) * cHS + hs) * cN;
            #pragma unroll
            for (int r = 0; r < 4; ++r) {
                const int n = n0 + r;
                const int pos = (n & ~31) + 2 * (n & 15) + ((n >> 4) & 1);
                vrow[pos] = f2bf(acc[c][r] + bias);
            }
        }
    }
}

// ---- Flash attention, fixed-max softmax (m=0), bit-masking, REGISTER-ONLY P.
// QK^T computed SWAPPED: s = mfma(K, Q) -> lane(col,grp) holds
// P[key = 4*grp + r (+16)][query = col]. Those 8 values per qs are exactly the
// PV A-fragment for lane(col,grp) under the V k'-permutation, so P never
// touches LDS: register exp2/cvt_pk/mask -> PV MFMA directly. Masks: 2 words
// per lane per kt (query col and col+16). No barriers in the k-loop.
// Grid = 1024 blocks x 2 sequential q-tile tasks; 4 waves split the key range;
// partials additive (fixed-max), combined via 16 KB LDS in two phases.
__global__ __launch_bounds__(256, 4) void attn_kernel(const unsigned short* __restrict__ Qb,
                                                      const unsigned short* __restrict__ Kb,
                                                      const unsigned short* __restrict__ Vt,
                                                      const unsigned int* __restrict__ mask32,
                                                      float* __restrict__ out) {
    __shared__ float comb[4][16][64];                // 16 KB combine buffer
    const int wv = threadIdx.x >> 6, lane = threadIdx.x & 63;
    const int col = lane & 15, grp = lane >> 4;
    int bid = blockIdx.x;
    bid = (bid & 7) * 128 + (bid >> 3);              // XCD chunk swizzle (1024 = 8*128)
    const int qt0 = bid & 63, h = (bid >> 6) & 7, b = bid >> 9;
    const unsigned short* Qh = Qb + (size_t)(b * cH + h) * cN * cHS;
    const unsigned short* Kh = Kb + (size_t)(b * cH + h) * cN * cHS;
    const unsigned short* Vh = Vt + (size_t)(b * cH + h) * cHS * cN;
    const f32x4 z4 = {0.f, 0.f, 0.f, 0.f};
    const short8 ones = { 0x3F80, 0x3F80, 0x3F80, 0x3F80, 0x3F80, 0x3F80, 0x3F80, 0x3F80 };
    const int kt0 = wv * 32;

    #pragma unroll 1
    for (int tk = 0; tk < 2; ++tk) {
        const int qbase = (qt0 + tk * 64) * 32;
        // mask row pointers for this lane's two queries (qbase+col, qbase+16+col)
        const unsigned int* m0 = mask32 + (size_t)(b * cN + qbase + col) * 128;
        const unsigned int* m1 = m0 + 16 * 128;

        const short8 aq0 = *(const short8*)(Qh + (size_t)(qbase + col) * cHS + grp * 8);
        const short8 aq1 = *(const short8*)(Qh + (size_t)(qbase + 16 + col) * cHS + grp * 8);

        f32x4 acc[2][2] = {};
        f32x4 lacc[2] = {};                          // row-sums via ones-MFMA

        #pragma unroll 1
        for (int kt = kt0; kt < kt0 + 32; ++kt) {
            const int kbase = kt * 32;
            const short8 k0 = *(const short8*)(Kh + (size_t)(kbase + col) * cHS + grp * 8);
            const short8 k1 = *(const short8*)(Kh + (size_t)(kbase + 16 + col) * cHS + grp * 8);
            const short8 v0 = *(const short8*)(Vh + (size_t)col * cN + kbase + grp * 8);
            const short8 v1 = *(const short8*)(Vh + (size_t)(16 + col) * cN + kbase + grp * 8);
            const unsigned int w0 = m0[kt];
            const unsigned int w1 = m1[kt];

            // swapped QK^T: D[m=key][n=query]
            f32x4 sA[2], sB[2];
            sA[0] = __builtin_amdgcn_mfma_f32_16x16x32_bf16(k0, aq0, z4, 0, 0, 0); // keys lo, q0-15
            sB[0] = __builtin_amdgcn_mfma_f32_16x16x32_bf16(k1, aq0, z4, 0, 0, 0); // keys hi, q0-15
            sA[1] = __builtin_amdgcn_mfma_f32_16x16x32_bf16(k0, aq1, z4, 0, 0, 0); // keys lo, q16-31
            sB[1] = __builtin_amdgcn_mfma_f32_16x16x32_bf16(k1, aq1, z4, 0, 0, 0); // keys hi, q16-31

            #pragma unroll
            for (int qs = 0; qs < 2; ++qs) {
                const unsigned int w = qs ? w1 : w0;
                u32x4 pu;
                #pragma unroll
                for (int j = 0; j < 4; ++j) {
                    const float e0 = __builtin_exp2f(sA[qs][j]);   // key 4g+j
                    const float e1 = __builtin_exp2f(sB[qs][j]);   // key 16+4g+j
                    const unsigned int msk = ((w >> (4 * grp + j)) & 0x00010001u) * 0xFFFFu;
                    pu[j] = cvt_pk_bf16(e0, e1) & msk;
                }
                const short8 pa = __builtin_bit_cast(short8, pu);
                acc[qs][0] = __builtin_amdgcn_mfma_f32_16x16x32_bf16(pa, v0, acc[qs][0], 0, 0, 0);
                acc[qs][1] = __builtin_amdgcn_mfma_f32_16x16x32_bf16(pa, v1, acc[qs][1], 0, 0, 0);
                lacc[qs]   = __builtin_amdgcn_mfma_f32_16x16x32_bf16(pa, ones, lacc[qs], 0, 0, 0);
            }
        }

        // ---- two-phase combine through 16 KB LDS ----
        __syncthreads();                             // comb free (prev task done)
        #pragma unroll
        for (int qs = 0; qs < 2; ++qs)
            #pragma unroll
            for (int hf = 0; hf < 2; ++hf)
                #pragma unroll
                for (int j = 0; j < 4; ++j)
                    comb[wv][(qs * 2 + hf) * 4 + j][lane] = acc[qs][hf][j];
        __syncthreads();
        const int sg = wv, qs2 = sg >> 1, half = sg & 1;
        f32x4 a = {0.f, 0.f, 0.f, 0.f};
        #pragma unroll
        for (int w = 0; w < 4; ++w)
            #pragma unroll
            for (int j = 0; j < 4; ++j)
                a[j] += comb[w][sg * 4 + j][lane];
        __syncthreads();
        #pragma unroll
        for (int qs = 0; qs < 2; ++qs)
            #pragma unroll
            for (int j = 0; j < 4; ++j)
                comb[wv][qs * 4 + j][lane] = lacc[qs][j];
        __syncthreads();
        f32x4 l = {0.f, 0.f, 0.f, 0.f};
        #pragma unroll
        for (int w = 0; w < 4; ++w)
            #pragma unroll
            for (int j = 0; j < 4; ++j)
                l[j] += comb[w][qs2 * 4 + j][lane];

        const int row0 = qbase + qs2 * 16 + grp * 4;
        #pragma unroll
        for (int j = 0; j < 4; ++j) {
            out[(size_t)(b * cN + row0 + j) * cE + h * 32 + half * 16 + col] = a[j] / l[j];
        }
        __syncthreads();                             // protect comb for next task
    }
}

extern "C" void kernel_launch(void* const* d_in, const int* in_sizes, int n_in,
                              void* d_out, int out_size, void* d_ws, size_t ws_size,
                              hipStream_t stream) {
    const float* x   = (const float*)d_in[0];
    const int*   adj = (const int*)d_in[1];
    const float* Wq  = (const float*)d_in[2];
    const float* bq  = (const float*)d_in[3];
    const float* Wk  = (const float*)d_in[4];
    const float* bk  = (const float*)d_in[5];
    const float* Wv  = (const float*)d_in[6];
    const float* bv  = (const float*)d_in[7];
    float* out = (float*)d_out;

    char* ws = (char*)d_ws;
    unsigned short* Xb  = (unsigned short*)(ws);                       // 4 MB
    unsigned short* Wcb = (unsigned short*)(ws + (4ull << 20));        // 384 KB
    unsigned short* Qb  = (unsigned short*)(ws + (5ull << 20));        // 4 MB
    unsigned short* Kb  = (unsigned short*)(ws + (9ull << 20));        // 4 MB
    unsigned short* Vt  = (unsigned short*)(ws + (13ull << 20));       // 4 MB
    unsigned long long* mask64 = (unsigned long long*)(ws + (17ull << 20)); // 4 MB

    cvt_x_kernel<<<dim3(2048), dim3(256), 0, stream>>>(x, Xb);
    cvt_w_kernel<<<dim3(192), dim3(256), 0, stream>>>(Wq, Wk, Wv, Wcb);
    bitpack_kernel<<<dim3(2048), dim3(256), 0, stream>>>(adj, mask64);
    qkv_proj_kernel<<<dim3(128, 12), dim3(256), 0, stream>>>(Xb, Wcb, bq, bk, bv, Qb, Kb, Vt);
    attn_kernel<<<dim3(1024), dim3(256), 0, stream>>>(Qb, Kb, Vt, (const unsigned int*)mask64, out);
}

// Round 8
// 217.294 us; speedup vs baseline: 1.0060x; 1.0060x over previous
//
#include <hip/hip_runtime.h>

typedef __attribute__((ext_vector_type(8))) short short8;
typedef __attribute__((ext_vector_type(4))) float f32x4;
typedef __attribute__((ext_vector_type(4))) unsigned int u32x4;
typedef __attribute__((ext_vector_type(4))) unsigned short u16x4;

constexpr int cB = 2, cN = 4096, cE = 256, cH = 8, cHS = 32;

__device__ __forceinline__ unsigned short f2bf(float f) {
    unsigned int u = __builtin_bit_cast(unsigned int, f);
    u = (u + 0x7FFFu + ((u >> 16) & 1u)) >> 16;
    return (unsigned short)u;
}

__device__ __forceinline__ unsigned int cvt_pk_bf16(float lo, float hi) {
    unsigned int r;
    asm("v_cvt_pk_bf16_f32 %0, %1, %2" : "=v"(r) : "v"(lo), "v"(hi));
    return r;
}

// raw v_exp_f32 (D = 2^S0), no denormal-range guard code. Safe: |input| < 30.
__device__ __forceinline__ float exp2_raw(float x) {
    float r;
    asm("v_exp_f32 %0, %1" : "=v"(r) : "v"(x));
    return r;
}

// ---- f32 -> bf16 convert: node features (2M elems, 4/thread) ----
__global__ __launch_bounds__(256) void cvt_x_kernel(const float* __restrict__ x,
                                                    unsigned short* __restrict__ xb) {
    int t = blockIdx.x * 256 + threadIdx.x;   // 524288 threads exactly
    f32x4 v = *((const f32x4*)x + t);
    u16x4 o = { f2bf(v[0]), f2bf(v[1]), f2bf(v[2]), f2bf(v[3]) };
    *((u16x4*)xb + t) = o;
}

// ---- f32 -> bf16 convert: Wq|Wk|Wv -> Wcb[768][256] ----
__global__ __launch_bounds__(256) void cvt_w_kernel(const float* __restrict__ Wq,
                                                    const float* __restrict__ Wk,
                                                    const float* __restrict__ Wv,
                                                    unsigned short* __restrict__ wcb) {
    int t = blockIdx.x * 256 + threadIdx.x;   // 49152 threads exactly
    int f = t * 4;
    int o = f >> 8, i = f & 255;
    const float* src = (o < 256) ? Wq : (o < 512 ? Wk : Wv);
    f32x4 v = *(const f32x4*)(src + (size_t)(o & 255) * 256 + i);
    u16x4 ov = { f2bf(v[0]), f2bf(v[1]), f2bf(v[2]), f2bf(v[3]) };
    *((u16x4*)wcb + t) = ov;
}

// ---- adjacency (4-byte elems, nonzero == edge) -> bitmask, 64 bits/wave ----
__global__ __launch_bounds__(256) void bitpack_kernel(const int* __restrict__ adj,
                                                      unsigned long long* __restrict__ mask) {
    int lane = threadIdx.x & 63;
    int wave = blockIdx.x * 4 + (threadIdx.x >> 6);
    const int nwaves = 2048 * 4;
    const int nwords = cB * cN * cN / 64;     // 524288
    for (int w = wave; w < nwords; w += nwaves) {
        int v = adj[(size_t)w * 64 + lane];
        unsigned long long bal = __ballot(v != 0);
        if (lane == 0) mask[w] = bal;
    }
}

// ---- QKV projection: C[8192][768] = Xb @ Wcb^T + bias, MFMA 16x16x32 bf16 ----
// Q stored [b][h][n][32] bf16, PRE-SCALED by log2(e)/sqrt(HS) so attention can
// use exp2 on the raw QK^T output. K stored [b][h][n][32].
// V stored transposed AND k'-permuted within each 32-block of n:
//   Vt[h][hs][ (n&~31) + 2*(n&15) + ((n>>4)&1) ] = V[n][hs]
// matching the in-register P fragment order of the swapped-QK^T attention
// (lane elem e of group g holds key 4g+(e>>1)+16*(e&1)).
__global__ __launch_bounds__(256) void qkv_proj_kernel(const unsigned short* __restrict__ xb,
                                                       const unsigned short* __restrict__ wcb,
                                                       const float* __restrict__ bq,
                                                       const float* __restrict__ bk,
                                                       const float* __restrict__ bv,
                                                       unsigned short* __restrict__ Qb,
                                                       unsigned short* __restrict__ Kb,
                                                       unsigned short* __restrict__ Vt) {
    const int wv = threadIdx.x >> 6, lane = threadIdx.x & 63;
    const int col = lane & 15, grp = lane >> 4;
    const int rowbase = blockIdx.x * 64 + wv * 16;   // 16 rows per wave
    const int colbase = blockIdx.y * 64;             // 64 cols per block
    const float CE = 1.4426950408889634f * 0.17677669529663687f;  // log2(e)/sqrt(32)
    f32x4 acc[4] = {};
    for (int kk = 0; kk < 8; ++kk) {
        short8 a = *(const short8*)(xb + (size_t)(rowbase + col) * 256 + kk * 32 + grp * 8);
        #pragma unroll
        for (int c = 0; c < 4; ++c) {
            short8 bf = *(const short8*)(wcb + (size_t)(colbase + c * 16 + col) * 256 + kk * 32 + grp * 8);
            acc[c] = __builtin_amdgcn_mfma_f32_16x16x32_bf16(a, bf, acc[c], 0, 0, 0);
        }
    }
    #pragma unroll
    for (int c = 0; c < 4; ++c) {
        const int o = colbase + c * 16 + col;        // lane's output column
        const int sel = o >> 8, oo = o & 255;
        const float bias = (sel == 0 ? bq : sel == 1 ? bk : bv)[oo];
        const int h = oo >> 5, hs = oo & 31;
        const int R0 = rowbase + grp * 4;            // 4 consecutive rows per lane
        const int b = R0 >> 12, n0 = R0 & 4095;
        if (sel == 0) {
            #pragma unroll
            for (int r = 0; r < 4; ++r)
                Qb[(size_t)((b * cH + h) * cN + n0 + r) * cHS + hs] = f2bf((acc[c][r] + bias) * CE);
        } else if (sel == 1) {
            #pragma unroll
            for (int r = 0; r < 4; ++r)
                Kb[(size_t)((b * cH + h) * cN + n0 + r) * cHS + hs] = f2bf(acc[c][r] + bias);
        } else {
            unsigned short* vrow = Vt + (size_t)((b * cH + h) * cHS + hs) * cN;
            #pragma unroll
            for (int r = 0; r < 4; ++r) {
                const int n = n0 + r;
                const int pos = (n & ~31) + 2 * (n & 15) + ((n >> 4) & 1);
                vrow[pos] = f2bf(acc[c][r] + bias);
            }
        }
    }
}

// ---- Flash attention, fixed-max softmax (m=0), bit-masking, REGISTER-ONLY P.
// QK^T computed SWAPPED: s = mfma(K, Q) -> lane(col,grp) holds
// P[key = 4*grp + r (+16)][query = col]; exactly the PV A-fragment under the
// V k'-permutation -> P never touches LDS. One-ahead register prefetch of
// K/V/mask (affordable now: ~100 total regs < LB(256,4)'s 128 cap); raw
// v_exp_f32 (no guard expansion). No barriers in the k-loop.
// Grid = 1024 blocks x 2 sequential q-tile tasks; 4 waves split the key range;
// partials additive (fixed-max), combined via 16 KB LDS in two phases.
__global__ __launch_bounds__(256, 4) void attn_kernel(const unsigned short* __restrict__ Qb,
                                                      const unsigned short* __restrict__ Kb,
                                                      const unsigned short* __restrict__ Vt,
                                                      const unsigned int* __restrict__ mask32,
                                                      float* __restrict__ out) {
    __shared__ float comb[4][16][64];                // 16 KB combine buffer
    const int wv = threadIdx.x >> 6, lane = threadIdx.x & 63;
    const int col = lane & 15, grp = lane >> 4;
    int bid = blockIdx.x;
    bid = (bid & 7) * 128 + (bid >> 3);              // XCD chunk swizzle (1024 = 8*128)
    const int qt0 = bid & 63, h = (bid >> 6) & 7, b = bid >> 9;
    const unsigned short* Qh = Qb + (size_t)(b * cH + h) * cN * cHS;
    const unsigned short* Kh = Kb + (size_t)(b * cH + h) * cN * cHS;
    const unsigned short* Vh = Vt + (size_t)(b * cH + h) * cHS * cN;
    const f32x4 z4 = {0.f, 0.f, 0.f, 0.f};
    const short8 ones = { 0x3F80, 0x3F80, 0x3F80, 0x3F80, 0x3F80, 0x3F80, 0x3F80, 0x3F80 };
    const int kt0 = wv * 32;

    #pragma unroll 1
    for (int tk = 0; tk < 2; ++tk) {
        const int qbase = (qt0 + tk * 64) * 32;
        // mask row pointers for this lane's two queries (qbase+col, qbase+16+col)
        const unsigned int* m0 = mask32 + (size_t)(b * cN + qbase + col) * 128;
        const unsigned int* m1 = m0 + 16 * 128;

        const short8 aq0 = *(const short8*)(Qh + (size_t)(qbase + col) * cHS + grp * 8);
        const short8 aq1 = *(const short8*)(Qh + (size_t)(qbase + 16 + col) * cHS + grp * 8);

        f32x4 acc[2][2] = {};
        f32x4 lacc[2] = {};                          // row-sums via ones-MFMA

        // prologue: load kt0's K/V/mask into "current" regs
        short8 kc0 = *(const short8*)(Kh + (size_t)(kt0 * 32 + col) * cHS + grp * 8);
        short8 kc1 = *(const short8*)(Kh + (size_t)(kt0 * 32 + 16 + col) * cHS + grp * 8);
        short8 vc0 = *(const short8*)(Vh + (size_t)col * cN + kt0 * 32 + grp * 8);
        short8 vc1 = *(const short8*)(Vh + (size_t)(16 + col) * cN + kt0 * 32 + grp * 8);
        unsigned int wc0 = m0[kt0], wc1 = m1[kt0];

        #pragma unroll 1
        for (int kt = kt0; kt < kt0 + 32; ++kt) {
            // issue next-iteration loads first (clamped index; scalar select)
            const int ktn = (kt < kt0 + 31) ? kt + 1 : kt0;
            const int kbn = ktn * 32;
            const short8 kn0 = *(const short8*)(Kh + (size_t)(kbn + col) * cHS + grp * 8);
            const short8 kn1 = *(const short8*)(Kh + (size_t)(kbn + 16 + col) * cHS + grp * 8);
            const short8 vn0 = *(const short8*)(Vh + (size_t)col * cN + kbn + grp * 8);
            const short8 vn1 = *(const short8*)(Vh + (size_t)(16 + col) * cN + kbn + grp * 8);
            const unsigned int wn0 = m0[ktn], wn1 = m1[ktn];

            // swapped QK^T on CURRENT regs: D[m=key][n=query]
            f32x4 sA[2], sB[2];
            sA[0] = __builtin_amdgcn_mfma_f32_16x16x32_bf16(kc0, aq0, z4, 0, 0, 0);
            sB[0] = __builtin_amdgcn_mfma_f32_16x16x32_bf16(kc1, aq0, z4, 0, 0, 0);
            sA[1] = __builtin_amdgcn_mfma_f32_16x16x32_bf16(kc0, aq1, z4, 0, 0, 0);
            sB[1] = __builtin_amdgcn_mfma_f32_16x16x32_bf16(kc1, aq1, z4, 0, 0, 0);

            #pragma unroll
            for (int qs = 0; qs < 2; ++qs) {
                const unsigned int w = qs ? wc1 : wc0;
                u32x4 pu;
                #pragma unroll
                for (int j = 0; j < 4; ++j) {
                    const float e0 = exp2_raw(sA[qs][j]);          // key 4g+j
                    const float e1 = exp2_raw(sB[qs][j]);          // key 16+4g+j
                    const unsigned int msk = ((w >> (4 * grp + j)) & 0x00010001u) * 0xFFFFu;
                    pu[j] = cvt_pk_bf16(e0, e1) & msk;
                }
                const short8 pa = __builtin_bit_cast(short8, pu);
                acc[qs][0] = __builtin_amdgcn_mfma_f32_16x16x32_bf16(pa, vc0, acc[qs][0], 0, 0, 0);
                acc[qs][1] = __builtin_amdgcn_mfma_f32_16x16x32_bf16(pa, vc1, acc[qs][1], 0, 0, 0);
                lacc[qs]   = __builtin_amdgcn_mfma_f32_16x16x32_bf16(pa, ones, lacc[qs], 0, 0, 0);
            }
            kc0 = kn0; kc1 = kn1; vc0 = vn0; vc1 = vn1; wc0 = wn0; wc1 = wn1;
        }

        // ---- two-phase combine through 16 KB LDS ----
        __syncthreads();                             // comb free (prev task done)
        #pragma unroll
        for (int qs = 0; qs < 2; ++qs)
            #pragma unroll
            for (int hf = 0; hf < 2; ++hf)
                #pragma unroll
                for (int j = 0; j < 4; ++j)
                    comb[wv][(qs * 2 + hf) * 4 + j][lane] = acc[qs][hf][j];
        __syncthreads();
        const int sg = wv, qs2 = sg >> 1, half = sg & 1;
        f32x4 a = {0.f, 0.f, 0.f, 0.f};
        #pragma unroll
        for (int w = 0; w < 4; ++w)
            #pragma unroll
            for (int j = 0; j < 4; ++j)
                a[j] += comb[w][sg * 4 + j][lane];
        __syncthreads();
        #pragma unroll
        for (int qs = 0; qs < 2; ++qs)
            #pragma unroll
            for (int j = 0; j < 4; ++j)
                comb[wv][qs * 4 + j][lane] = lacc[qs][j];
        __syncthreads();
        f32x4 l = {0.f, 0.f, 0.f, 0.f};
        #pragma unroll
        for (int w = 0; w < 4; ++w)
            #pragma unroll
            for (int j = 0; j < 4; ++j)
                l[j] += comb[w][qs2 * 4 + j][lane];

        const int row0 = qbase + qs2 * 16 + grp * 4;
        #pragma unroll
        for (int j = 0; j < 4; ++j) {
            out[(size_t)(b * cN + row0 + j) * cE + h * 32 + half * 16 + col] = a[j] / l[j];
        }
        __syncthreads();                             // protect comb for next task
    }
}

extern "C" void kernel_launch(void* const* d_in, const int* in_sizes, int n_in,
                              void* d_out, int out_size, void* d_ws, size_t ws_size,
                              hipStream_t stream) {
    const float* x   = (const float*)d_in[0];
    const int*   adj = (const int*)d_in[1];
    const float* Wq  = (const float*)d_in[2];
    const float* bq  = (const float*)d_in[3];
    const float* Wk  = (const float*)d_in[4];
    const float* bk  = (const float*)d_in[5];
    const float* Wv  = (const float*)d_in[6];
    const float* bv  = (const float*)d_in[7];
    float* out = (float*)d_out;

    char* ws = (char*)d_ws;
    unsigned short* Xb  = (unsigned short*)(ws);                       // 4 MB
    unsigned short* Wcb = (unsigned short*)(ws + (4ull << 20));        // 384 KB
    unsigned short* Qb  = (unsigned short*)(ws + (5ull << 20));        // 4 MB
    unsigned short* Kb  = (unsigned short*)(ws + (9ull << 20));        // 4 MB
    unsigned short* Vt  = (unsigned short*)(ws + (13ull << 20));       // 4 MB
    unsigned long long* mask64 = (unsigned long long*)(ws + (17ull << 20)); // 4 MB

    cvt_x_kernel<<<dim3(2048), dim3(256), 0, stream>>>(x, Xb);
    cvt_w_kernel<<<dim3(192), dim3(256), 0, stream>>>(Wq, Wk, Wv, Wcb);
    bitpack_kernel<<<dim3(2048), dim3(256), 0, stream>>>(adj, mask64);
    qkv_proj_kernel<<<dim3(128, 12), dim3(256), 0, stream>>>(Xb, Wcb, bq, bk, bv, Qb, Kb, Vt);
    attn_kernel<<<dim3(1024), dim3(256), 0, stream>>>(Qb, Kb, Vt, (const unsigned int*)mask64, out);
}